// Round 1
// baseline (99.943 us; speedup 1.0000x reference)
//
#include <hip/hip_runtime.h>

#define B_ROWS 16384
#define I_DIM  512
#define O_DIM  64
#define NFEAT  8          // 2*K fourier features per x element
// W2t: [I_DIM][O_DIM][NFEAT] f16  (512 KB)   at d_ws + 0
// cst: [O_DIM] f32                           at d_ws + W2_BYTES
#define W2_BYTES ((size_t)I_DIM * O_DIM * NFEAT * 2)

typedef _Float16 f16x8 __attribute__((ext_vector_type(8)));
typedef float    f32x4 __attribute__((ext_vector_type(4)));

// ---------------- prep: W2[i*8+f][o] = w[o,i] * coef[o,i,f+1], f16 ----------------
__global__ __launch_bounds__(256) void prep_w2(const float* __restrict__ w,
                                               const float* __restrict__ coef,
                                               _Float16* __restrict__ w2) {
    int t = blockIdx.x * 256 + threadIdx.x;   // 0..32767 ; t = i*64 + o
    int i = t >> 6;
    int o = t & 63;
    float wv = w[o * I_DIM + i];
    const float* cp = coef + ((size_t)(o * I_DIM + i)) * 9;
    f16x8 v;
#pragma unroll
    for (int f = 0; f < 8; ++f) v[f] = (_Float16)(wv * cp[f + 1]);
    *reinterpret_cast<f16x8*>(w2 + (size_t)t * 8) = v;   // contiguous 16B per thread
}

// ---------------- prep: const[o] = sum_i w[o,i]*coef[o,i,0] ----------------
__global__ __launch_bounds__(64) void prep_const(const float* __restrict__ w,
                                                 const float* __restrict__ coef,
                                                 float* __restrict__ cst) {
    int o = blockIdx.x;
    int l = threadIdx.x;
    float s = 0.f;
    for (int i = l; i < I_DIM; i += 64)
        s += w[o * I_DIM + i] * coef[((size_t)(o * I_DIM + i)) * 9];
#pragma unroll
    for (int off = 32; off; off >>= 1) s += __shfl_down(s, off, 64);
    if (l == 0) cst[o] = s;
}

// ---------------- main: out[64 rows x 64 cols] per block ----------------
// 512 threads = 8 waves. Wave w handles K-slice i in [w*64, w*64+64), all 4 M-tiles
// (16 rows each) x 4 N-tiles (16 cols each). A-fragment for mfma_f32_16x16x32_f16:
// lane l holds A[row = l&15][k = (l>>4)*8 + j]; since k = i*8 + f, lane l's 8 k's are
// exactly the 8 features of x[rbase + mtile*16 + (l&15)][i0 + s*4 + (l>>4)].
__global__ __launch_bounds__(512) void fourier_main(const float* __restrict__ x,
                                                    const _Float16* __restrict__ w2,
                                                    const float* __restrict__ cst,
                                                    float* __restrict__ out) {
    __shared__ float red[4][64][64];   // 64 KB

    const int tid   = threadIdx.x;
    const int wave  = tid >> 6;
    const int lane  = tid & 63;
    const int col16 = lane & 15;   // A-row within tile / B,D column
    const int ig    = lane >> 4;   // i sub-offset 0..3 (k-chunk of fragment)
    const int rbase = blockIdx.x * 64;

    f32x4 acc[4][4] = {};          // [mtile][ntile], f32 accum
    const int i0 = wave * 64;      // this wave's K-slice (64 i's = 512 k's)

    const float* xr[4];
#pragma unroll
    for (int m = 0; m < 4; ++m)
        xr[m] = x + (size_t)(rbase + m * 16 + col16) * I_DIM;

    const f16x8* __restrict__ bbase = reinterpret_cast<const f16x8*>(w2);

    for (int s = 0; s < 16; ++s) {
        const int i = i0 + s * 4 + ig;

        // B fragments: lane reads 16B contiguous; 16-lane groups are 256B segments
        f16x8 bf[4];
#pragma unroll
        for (int n = 0; n < 4; ++n) bf[n] = bbase[i * 64 + n * 16 + col16];

        // x loads for the 4 M-tiles (independent, issue together)
        float xv[4];
#pragma unroll
        for (int m = 0; m < 4; ++m) xv[m] = xr[m][i];

#pragma unroll
        for (int m = 0; m < 4; ++m) {
            float s1, c1;
            __sincosf(xv[m], &s1, &c1);
            const float tc = 2.f * c1;
            const float s2 = tc * s1;          // sin2
            const float c2 = tc * c1 - 1.f;    // cos2
            const float s3 = tc * s2 - s1;     // sin3
            const float c3 = tc * c2 - c1;     // cos3
            const float s4 = tc * s3 - s2;     // sin4
            const float c4 = tc * c3 - c2;     // cos4
            f16x8 af;
            af[0] = (_Float16)s1; af[1] = (_Float16)c1;
            af[2] = (_Float16)s2; af[3] = (_Float16)c2;
            af[4] = (_Float16)s3; af[5] = (_Float16)c3;
            af[6] = (_Float16)s4; af[7] = (_Float16)c4;
#pragma unroll
            for (int n = 0; n < 4; ++n)
                acc[m][n] = __builtin_amdgcn_mfma_f32_16x16x32_f16(af, bf[n], acc[m][n], 0, 0, 0);
        }
    }

    // ---- epilogue: 8 K-slices -> 4 LDS slices -> sum + const -> out ----
    // D layout: within-tile row = ig*4 + q, col = col16.
    if (wave < 4) {
#pragma unroll
        for (int m = 0; m < 4; ++m)
#pragma unroll
            for (int n = 0; n < 4; ++n)
#pragma unroll
                for (int q = 0; q < 4; ++q)
                    red[wave][m * 16 + ig * 4 + q][n * 16 + col16] = acc[m][n][q];
    }
    __syncthreads();
    if (wave >= 4) {
#pragma unroll
        for (int m = 0; m < 4; ++m)
#pragma unroll
            for (int n = 0; n < 4; ++n)
#pragma unroll
                for (int q = 0; q < 4; ++q)
                    red[wave - 4][m * 16 + ig * 4 + q][n * 16 + col16] += acc[m][n][q];
    }
    __syncthreads();

    const float cv = cst[lane];            // col = tid&63 is constant per thread
#pragma unroll
    for (int j = 0; j < 8; ++j) {
        const int r = wave + 8 * j;        // rows 0..63
        const int c = lane;
        float v = cv + red[0][r][c] + red[1][r][c] + red[2][r][c] + red[3][r][c];
        out[(size_t)(rbase + r) * 64 + c] = v;
    }
}

extern "C" void kernel_launch(void* const* d_in, const int* in_sizes, int n_in,
                              void* d_out, int out_size, void* d_ws, size_t ws_size,
                              hipStream_t stream) {
    const float* x    = (const float*)d_in[0];
    const float* w    = (const float*)d_in[1];
    const float* coef = (const float*)d_in[2];
    _Float16* w2  = (_Float16*)d_ws;
    float*    cst = (float*)((char*)d_ws + W2_BYTES);
    float*    out = (float*)d_out;

    hipLaunchKernelGGL(prep_w2,    dim3(128), dim3(256), 0, stream, w, coef, w2);
    hipLaunchKernelGGL(prep_const, dim3(64),  dim3(64),  0, stream, w, coef, cst);
    hipLaunchKernelGGL(fourier_main, dim3(B_ROWS / 64), dim3(512), 0, stream, x, w2, cst, out);
}